// Round 1
// baseline (32.105 us; speedup 1.0000x reference)
//
#include <hip/hip_runtime.h>
#include <stdint.h>

#define NB 8
#define NH 256
#define NW 256
#define HWSZ 65536

// Distance from bit position x to nearest set bit in 256-bit word array w[4].
// Returns 512 if no set bit (acts as INF: 512^2=262144 > max real d2=130050).
__device__ __forceinline__ int nearest_dist(const unsigned long long w[4], int x) {
    int i = x >> 6, j = x & 63;
    int dl = 1 << 20, dr = 1 << 20;
    // left: bits <= x
    unsigned long long ml = w[i] & (~0ULL >> (63 - j));
    int il = i;
    while (ml == 0ULL && il > 0) { ml = w[--il]; }
    if (ml != 0ULL) {
        int h = 63 - __builtin_clzll(ml);
        dl = x - (il * 64 + h);
    }
    // right: bits >= x
    unsigned long long mr = w[i] & (~0ULL << j);
    int ir = i;
    while (mr == 0ULL && ir < 3) { mr = w[++ir]; }
    if (mr != 0ULL) {
        int l = __builtin_ctzll(mr);
        dr = (ir * 64 + l) - x;
    }
    int d = min(dl, dr);
    return min(d, 512);
}

// One block per (b,y) row. Builds the row's pos-bitmask via ballot, then each
// thread (one per x) computes 1D distance to nearest neg pixel (dn) and to
// nearest pos pixel (dp). Packed into one u32: dn | dp<<16.
__global__ __launch_bounds__(256) void row_kernel(const float* __restrict__ seg,
                                                  uint32_t* __restrict__ comb) {
    int blk = blockIdx.x;
    int b = blk >> 8, y = blk & 255;
    int x = threadIdx.x;
    const float* base = seg + (size_t)b * 3 * HWSZ + (size_t)y * NW;
    float s1 = base[HWSZ + x];
    float s2 = base[2 * HWSZ + x];
    bool pos = (s1 + s2) > 0.5f;
    unsigned long long bal = __ballot(pos);
    __shared__ unsigned long long wds[4];
    if ((x & 63) == 0) wds[x >> 6] = bal;
    __syncthreads();
    unsigned long long wp[4], wn[4];
#pragma unroll
    for (int i = 0; i < 4; i++) { wp[i] = wds[i]; wn[i] = ~wds[i]; }
    int dp = nearest_dist(wp, x);  // dist to nearest pos pixel -> neg_edt
    int dn = nearest_dist(wn, x);  // dist to nearest neg pixel -> pos_edt
    comb[(size_t)b * HWSZ + y * NW + x] = (uint32_t)dn | ((uint32_t)dp << 16);
}

// One block per (b, x-tile of 32, y-tile of 32). Stages full-height (256) x
// 32-wide tile of packed row distances in LDS, brute-force min over y' with
// all-integer mads, then computes the loss terms and block-reduces.
__global__ __launch_bounds__(256) void col_kernel(const uint32_t* __restrict__ comb,
                                                  const float* __restrict__ pred,
                                                  float* __restrict__ partials) {
    __shared__ uint32_t lds[256][32];
    int blk = blockIdx.x;           // 512 blocks
    int b = blk >> 6;
    int rem = blk & 63;
    int xt = (rem & 7) * 32;
    int yt = (rem >> 3) * 32;
    int t = threadIdx.x;

    const uint32_t* cbase = comb + (size_t)b * HWSZ + xt;
    {
        int r0 = t >> 3;            // 0..31
        int c4 = (t & 7) * 4;       // 0..28 step 4
#pragma unroll
        for (int rr = 0; rr < 8; rr++) {
            int r = r0 + rr * 32;
            uint4 v = *reinterpret_cast<const uint4*>(cbase + (size_t)r * NW + c4);
            *reinterpret_cast<uint4*>(&lds[r][c4]) = v;
        }
    }
    __syncthreads();

    int xl = t & 31;
    int yg = t >> 5;                // 0..7
    int y0 = yt + yg * 4;
    int d2n[4], d2p[4];
#pragma unroll
    for (int k = 0; k < 4; k++) { d2n[k] = 1 << 28; d2p[k] = 1 << 28; }

    for (int yp = 0; yp < 256; yp++) {
        uint32_t u = lds[yp][xl];
        int dn = (int)(u & 0xFFFFu);
        int dp = (int)(u >> 16);
#pragma unroll
        for (int k = 0; k < 4; k++) {
            int dy = (y0 + k) - yp;
            int dy2 = __mul24(dy, dy);
            int tn = __umul24(dn, dn) + dy2;
            int tp = __umul24(dp, dp) + dy2;
            d2n[k] = min(d2n[k], tn);
            d2p[k] = min(d2p[k], tp);
        }
    }

    float lsum = 0.0f;
    const float* pbase = pred + (size_t)b * HWSZ;
#pragma unroll
    for (int k = 0; k < 4; k++) {
        int y = y0 + k;
        float pe = sqrtf((float)d2n[k]);   // pos_edt: dist to nearest neg
        float ne = sqrtf((float)d2p[k]);   // neg_edt: dist to nearest pos
        float sdt = pe - ne;
        float pr = pbase[(size_t)y * NW + xt + xl];
        float wgt = __expf(-fabsf(sdt) * 0.2f);
        lsum += fabsf(pr - sdt) * wgt;
    }

    // deterministic block reduction
#pragma unroll
    for (int off = 32; off > 0; off >>= 1) lsum += __shfl_down(lsum, off, 64);
    __shared__ float wsum[4];
    if ((t & 63) == 0) wsum[t >> 6] = lsum;
    __syncthreads();
    if (t == 0) partials[blk] = (wsum[0] + wsum[1]) + (wsum[2] + wsum[3]);
}

__global__ __launch_bounds__(256) void final_kernel(const float* __restrict__ partials,
                                                    float* __restrict__ out) {
    int t = threadIdx.x;
    float s = partials[t] + partials[t + 256];
#pragma unroll
    for (int off = 32; off > 0; off >>= 1) s += __shfl_down(s, off, 64);
    __shared__ float wsum[4];
    if ((t & 63) == 0) wsum[t >> 6] = s;
    __syncthreads();
    if (t == 0) out[0] = ((wsum[0] + wsum[1]) + (wsum[2] + wsum[3])) * (1.0f / (NB * HWSZ));
}

extern "C" void kernel_launch(void* const* d_in, const int* in_sizes, int n_in,
                              void* d_out, int out_size, void* d_ws, size_t ws_size,
                              hipStream_t stream) {
    const float* pred = (const float*)d_in[0];   // (8,1,256,256) f32
    const float* seg  = (const float*)d_in[1];   // (8,3,256,256) f32
    float* out = (float*)d_out;                  // scalar f32

    uint32_t* comb = (uint32_t*)d_ws;                                // 2 MB
    float* partials = (float*)((char*)d_ws + (size_t)NB * HWSZ * 4); // 2 KB

    row_kernel<<<NB * NH, 256, 0, stream>>>(seg, comb);
    col_kernel<<<NB * (NW / 32) * (NH / 32), 256, 0, stream>>>(comb, pred, partials);
    final_kernel<<<1, 256, 0, stream>>>(partials, out);
}

// Round 2
// 30.198 us; speedup vs baseline: 1.0631x; 1.0631x over previous
//
#include <hip/hip_runtime.h>
#include <stdint.h>

#define NB 8
#define NH 256
#define NW 256
#define HWSZ 65536

struct Ctrl {
    unsigned long long accum;
    unsigned int cnt;
};

// Distance from bit position x to nearest set bit in 256-bit word array w[4].
// Returns 512 if no set bit (INF sentinel: 512^2=262144 > max real d2=130050).
__device__ __forceinline__ int nearest_dist(const unsigned long long w[4], int x) {
    int i = x >> 6, j = x & 63;
    int dl = 1 << 20, dr = 1 << 20;
    unsigned long long ml = w[i] & (~0ULL >> (63 - j));
    int il = i;
    while (ml == 0ULL && il > 0) { ml = w[--il]; }
    if (ml != 0ULL) {
        int h = 63 - __builtin_clzll(ml);
        dl = x - (il * 64 + h);
    }
    unsigned long long mr = w[i] & (~0ULL << j);
    int ir = i;
    while (mr == 0ULL && ir < 3) { mr = w[++ir]; }
    if (mr != 0ULL) {
        int l = __builtin_ctzll(mr);
        dr = (ir * 64 + l) - x;
    }
    int d = min(dl, dr);
    return min(d, 512);
}

// One block per (b,y) row: ballot-built 256-bit row mask, per-pixel 1D
// distances to nearest neg (dn) and nearest pos (dp), packed dn | dp<<16.
// Block 0 also zeroes the reduction control block (runs before col_kernel).
__global__ __launch_bounds__(256) void row_kernel(const float* __restrict__ seg,
                                                  uint32_t* __restrict__ comb,
                                                  Ctrl* __restrict__ ctrl) {
    if (blockIdx.x == 0 && threadIdx.x == 0) { ctrl->accum = 0ULL; ctrl->cnt = 0u; }
    int blk = blockIdx.x;
    int b = blk >> 8, y = blk & 255;
    int x = threadIdx.x;
    const float* base = seg + (size_t)b * 3 * HWSZ + (size_t)y * NW;
    float s1 = base[HWSZ + x];
    float s2 = base[2 * HWSZ + x];
    bool pos = (s1 + s2) > 0.5f;
    unsigned long long bal = __ballot(pos);
    __shared__ unsigned long long wds[4];
    if ((x & 63) == 0) wds[x >> 6] = bal;
    __syncthreads();
    unsigned long long wp[4], wn[4];
#pragma unroll
    for (int i = 0; i < 4; i++) { wp[i] = wds[i]; wn[i] = ~wds[i]; }
    int dp = nearest_dist(wp, x);  // dist to nearest pos pixel -> neg_edt
    int dn = nearest_dist(wn, x);  // dist to nearest neg pixel -> pos_edt
    comb[(size_t)b * HWSZ + y * NW + x] = (uint32_t)dn | ((uint32_t)dp << 16);
}

// One block per (b, x-tile 32, y-tile 32). Stages the full-height 256x32
// packed-distance tile in LDS (column XOR-swizzled: conflict-free b128 writes
// AND reads), scans a near yp-window first, block-votes, and only scans the
// far rows if some chain's best d^2 exceeds the provable far-candidate floor
// (49^2). Exact regardless of data. Loss fused; u64 fixed-point atomic sum;
// last block finalizes out[0].
__global__ __launch_bounds__(256) void col_kernel(const uint32_t* __restrict__ comb,
                                                  const float* __restrict__ pred,
                                                  Ctrl* __restrict__ ctrl,
                                                  float* __restrict__ out) {
    __shared__ uint32_t lds[256][32];
    __shared__ int wflag[4];
    __shared__ float wsum[4];
    int blk = blockIdx.x;           // 512 blocks
    int b = blk >> 6;
    int rem = blk & 63;
    int xt = (rem & 7) * 32;
    int yt = (rem >> 3) * 32;
    int t = threadIdx.x;

    const uint32_t* cbase = comb + (size_t)b * HWSZ + xt;
    {
        int r0 = t >> 3;            // 0..31
        int c4 = (t & 7) * 4;       // 0..28 step 4
#pragma unroll
        for (int rr = 0; rr < 8; rr++) {
            int r = r0 + rr * 32;
            uint4 v = *reinterpret_cast<const uint4*>(cbase + (size_t)r * NW + c4);
            *reinterpret_cast<uint4*>(&lds[r][c4 ^ ((r & 7) << 2)]) = v;
        }
    }
    if (t < 4) wflag[t] = 0;
    __syncthreads();

    int xl = t & 31;
    int yg = t >> 5;                // 0..7
    int y0 = yt + yg * 4;
    int d2n[4], d2p[4];
#pragma unroll
    for (int k = 0; k < 4; k++) { d2n[k] = 1 << 28; d2p[k] = 1 << 28; }

    // 2-yp unrolled scan: mad24 (dy*dy + g2) + min3 folding. Ranges always even.
#define SCAN2(lo, hi)                                                         \
    for (int yp = (lo); yp < (hi); yp += 2) {                                 \
        uint32_t ua = lds[yp][xl ^ ((yp & 7) << 2)];                          \
        uint32_t ub = lds[yp + 1][xl ^ (((yp + 1) & 7) << 2)];                \
        int dna = (int)(ua & 0xFFFFu), dpa = (int)(ua >> 16);                 \
        int dnb = (int)(ub & 0xFFFFu), dpb = (int)(ub >> 16);                 \
        int n2a = __mul24(dna, dna), p2a = __mul24(dpa, dpa);                 \
        int n2b = __mul24(dnb, dnb), p2b = __mul24(dpb, dpb);                 \
        _Pragma("unroll")                                                     \
        for (int k = 0; k < 4; k++) {                                         \
            int dya = y0 + k - yp;                                            \
            int dyb = dya - 1;                                                \
            d2n[k] = min(d2n[k], min(__mul24(dya, dya) + n2a,                 \
                                     __mul24(dyb, dyb) + n2b));               \
            d2p[k] = min(d2p[k], min(__mul24(dya, dya) + p2a,                 \
                                     __mul24(dyb, dyb) + p2b));               \
        }                                                                     \
    }

    int lo1 = yt - 48; if (lo1 < 0) lo1 = 0;
    int hi1 = yt + 80; if (hi1 > 256) hi1 = 256;
    SCAN2(lo1, hi1)

    // Vote: any unscanned yp has |dy| >= 49 -> d2 >= 2401. Skip far scan iff
    // every chain in the block is already <= 2401.
    int m = 0;
#pragma unroll
    for (int k = 0; k < 4; k++) { m = max(m, d2n[k]); m = max(m, d2p[k]); }
    int more = __any(m > 2401) ? 1 : 0;
    if ((t & 63) == 0) wflag[t >> 6] = more;
    __syncthreads();
    if ((wflag[0] | wflag[1] | wflag[2] | wflag[3]) != 0) {
        SCAN2(0, lo1)
        SCAN2(hi1, 256)
    }
#undef SCAN2

    float lsum = 0.0f;
    const float* pbase = pred + (size_t)b * HWSZ + xt;
#pragma unroll
    for (int k = 0; k < 4; k++) {
        int y = y0 + k;
        float pe = sqrtf((float)d2n[k]);   // pos_edt: dist to nearest neg
        float ne = sqrtf((float)d2p[k]);   // neg_edt: dist to nearest pos
        float sdt = pe - ne;
        float pr = pbase[(size_t)y * NW + xl];
        float wgt = __expf(-fabsf(sdt) * 0.2f);
        lsum += fabsf(pr - sdt) * wgt;
    }

    // Deterministic block reduction -> fixed-point u64 device sum.
#pragma unroll
    for (int off = 32; off > 0; off >>= 1) lsum += __shfl_down(lsum, off, 64);
    if ((t & 63) == 0) wsum[t >> 6] = lsum;
    __syncthreads();
    if (t == 0) {
        float bs = (wsum[0] + wsum[1]) + (wsum[2] + wsum[3]);
        unsigned long long q = (unsigned long long)(bs * 1048576.0f);
        atomicAdd(&ctrl->accum, q);
        __threadfence();
        unsigned int old = atomicAdd(&ctrl->cnt, 1u);
        if (old == (unsigned int)(gridDim.x - 1)) {
            __threadfence();
            unsigned long long s = atomicAdd(&ctrl->accum, 0ULL);
            out[0] = (float)((double)s * (1.0 / 1048576.0) / (double)((size_t)NB * HWSZ));
        }
    }
}

extern "C" void kernel_launch(void* const* d_in, const int* in_sizes, int n_in,
                              void* d_out, int out_size, void* d_ws, size_t ws_size,
                              hipStream_t stream) {
    const float* pred = (const float*)d_in[0];   // (8,1,256,256) f32
    const float* seg  = (const float*)d_in[1];   // (8,3,256,256) f32
    float* out = (float*)d_out;                  // scalar f32

    uint32_t* comb = (uint32_t*)d_ws;                              // 2 MB
    Ctrl* ctrl = (Ctrl*)((char*)d_ws + (size_t)NB * HWSZ * 4);

    row_kernel<<<NB * NH, 256, 0, stream>>>(seg, comb, ctrl);
    col_kernel<<<NB * (NW / 32) * (NH / 32), 256, 0, stream>>>(comb, pred, ctrl, out);
}